// Round 13
// baseline (546.204 us; speedup 1.0000x reference)
//
#include <hip/hip_runtime.h>
#include <cstdint>
#include <cstddef>

// MemoryEfficientAttention: B=2, S=2048, D=1024, H=16, Dh=64
// R13: SINGLE persistent kernel (4 phases + 3 manual grid barriers).
// R8-derived budget: kernels ~131 us, launch gaps ~35 us (4 launches x
// ~9 us) -- the biggest untouched lever. Phases reuse only proven bodies:
//   p0 cvt (grid-stride), p1 gemm0 128x128 2D-XCD (R11), p2 attn v13
//   (R12-verified 256-thr), p3 gemm1 64x64 KU=2 2D-XCD (R11).
// Co-residency: 1024 blocks = exactly 4/CU; launch_bounds(256,4) caps
// VGPR at 128 (gemm0 restructured ks-outer so acc64+ops32 fits); LDS
// union = 32 KB -> 4/CU. Barriers: agent-scope release (threadfence =
// wbl2) -> atomic arrive -> relaxed spin -> acquire fence (inv) --
// replicates the inter-dispatch cache protocol (Guideline 16 / XCD L2
// non-coherence). Counters memset per launch (graph-capturable).

typedef unsigned short u16;
typedef unsigned int u32;
typedef __bf16 bf16x8 __attribute__((ext_vector_type(8)));
typedef float f32x4 __attribute__((ext_vector_type(4)));

#define GLOAD_LDS16(gp, lp)                                                            \
  __builtin_amdgcn_global_load_lds((const __attribute__((address_space(1))) void*)(gp),\
                                   (__attribute__((address_space(3))) void*)(lp),      \
                                   16, 0, 0)

__device__ __forceinline__ u16 f2bf(float f) {  // round-to-nearest-even
  unsigned u = __builtin_bit_cast(unsigned, f);
  u = u + 0x7fffu + ((u >> 16) & 1u);
  return (u16)(u >> 16);
}

// two f32 -> packed bf16x2 (lo = a, hi = b), RNE, 1 instruction (gfx950)
__device__ __forceinline__ u32 cvtpk(float a, float b) {
  u32 r;
  asm("v_cvt_pk_bf16_f32 %0, %1, %2" : "=v"(r) : "v"(a), "v"(b));
  return r;
}

// scale folded into Q: attn uses exp2, so fold log2(e) too
#define QSCALE 0.1803368801111204f   // 0.125 * log2(e)

// LDS union across phases (max 32 KB -> 4 blocks/CU)
union MegaSmem {
  struct { u16 As[128 * 64]; u16 Bs[128 * 64]; } g0;        // gemm0: 32 KB
  struct { u16 As[2][64 * 64]; u16 Bs[2][64 * 64]; } g1;    // gemm1: 32 KB
  struct { u16 K[2][64 * 64]; u16 V[2][64 * 64]; } am;      // attn:  32 KB
  struct { float O[2][32 * 64]; float L[2][32]; } af;       // attn combine
};

// device-scope grid barrier (all 1024 blocks co-resident by construction).
// Release: threadfence (agent: wbl2 of this XCD's dirty lines) before the
// acq_rel arrive; consumers spin relaxed then acquire-fence (inv) once.
__device__ __forceinline__ void gbar(u32* c, u32 nblk) {
  __syncthreads();   // block's stores issued (s_barrier drains vmcnt)
  if (threadIdx.x == 0) {
    __threadfence();
    __hip_atomic_fetch_add(c, 1u, __ATOMIC_ACQ_REL, __HIP_MEMORY_SCOPE_AGENT);
    while (__hip_atomic_load(c, __ATOMIC_RELAXED, __HIP_MEMORY_SCOPE_AGENT) < nblk)
      __builtin_amdgcn_s_sleep(2);
    __threadfence();
  }
  __syncthreads();
}

__global__ __launch_bounds__(256, 4) void mega(
    const float* __restrict__ x,
    const float* __restrict__ Wq, const float* __restrict__ bq,
    const float* __restrict__ Wk, const float* __restrict__ bk,
    const float* __restrict__ Wv, const float* __restrict__ bv,
    const float* __restrict__ Wo, const float* __restrict__ bo,
    u16* __restrict__ xb, u16* __restrict__ wqb, u16* __restrict__ wkb,
    u16* __restrict__ wvb, u16* __restrict__ wob,
    u16* __restrict__ Qb, u16* __restrict__ Kb, u16* __restrict__ VTb,
    u16* __restrict__ AOb, float* __restrict__ y, u32* __restrict__ ctr)
{
  __shared__ __align__(16) MegaSmem sm;

  const int tid = threadIdx.x;
  const int idb = blockIdx.x;           // 0..1023
  const int w = tid >> 6, l = tid & 63;
  const int lane = l & 15, quad = l >> 4;
  const int c8 = ((l & 7) ^ (l >> 3)) * 8;
  const int lrow = l >> 3;

  // ======================= phase 0: cvt (4096 units) =======================
  for (int u = idb; u < 4096; u += 1024) {
    const float* s; u16* d; int off;
    if (u < 2048)      { s = x;  d = xb;  off = u; }
    else if (u < 2560) { s = Wq; d = wqb; off = u - 2048; }
    else if (u < 3072) { s = Wk; d = wkb; off = u - 2560; }
    else if (u < 3584) { s = Wv; d = wvb; off = u - 3072; }
    else               { s = Wo; d = wob; off = u - 3584; }
    int i = off * 2048 + tid * 8;
    float4 a = *(const float4*)(s + i);
    float4 b = *(const float4*)(s + i + 4);
    uint4 o;
    o.x = f2bf(a.x) | ((u32)f2bf(a.y) << 16);
    o.y = f2bf(a.z) | ((u32)f2bf(a.w) << 16);
    o.z = f2bf(b.x) | ((u32)f2bf(b.y) << 16);
    o.w = f2bf(b.z) | ((u32)f2bf(b.w) << 16);
    *(uint4*)(d + i) = o;
  }
  gbar(ctr + 0, 1024);

  // ============ phase 1: gemm0 QKV, 128x128, 768 jobs (2D XCD) ============
  if (idb < 768) {
    const int xcd = idb & 7, j = idb >> 3;
    const int m_idx = (xcd >> 1) * 8 + (j & 7);        // 32 m-tiles
    const int n_idx = (xcd & 1) * 12 + (j >> 3);       // 24 n-tiles
    const int m0 = m_idx * 128;
    const int n0g = n_idx * 128;
    const int src = n0g >> 10;
    const u16* Wsel = (src == 0) ? wqb : (src == 1 ? wkb : wvb);
    const float* bsel = (src == 0) ? bq : (src == 1 ? bk : bv);
    const int n_base = n0g & 1023;
    const int wm = w >> 1, wn = w & 1;

    f32x4 acc[4][4] = {};

    for (int kt = 0; kt < 1024; kt += 64) {
      __syncthreads();
      const u16* Ag = xb + (size_t)m0 * 1024 + kt;
      const u16* Bg = Wsel + (size_t)n_base * 1024 + kt;
      #pragma unroll
      for (int i = 0; i < 4; ++i) {
        int rr = w * 32 + i * 8;
        GLOAD_LDS16(Ag + (size_t)(rr + lrow) * 1024 + c8, sm.g0.As + rr * 64);
        GLOAD_LDS16(Bg + (size_t)(rr + lrow) * 1024 + c8, sm.g0.Bs + rr * 64);
      }
      __syncthreads();

      // ks-outer: only 8 operand frags live at a time (VGPR cap 128)
      #pragma unroll
      for (int ks = 0; ks < 2; ++ks) {
        bf16x8 af[4], bf[4];
        #pragma unroll
        for (int mf = 0; mf < 4; ++mf)
          af[mf] = *(const bf16x8*)((const char*)sm.g0.As +
              (wm * 64 + mf * 16 + lane) * 128 + (((ks * 4 + quad) ^ (lane & 7)) * 16));
        #pragma unroll
        for (int nf = 0; nf < 4; ++nf)
          bf[nf] = *(const bf16x8*)((const char*)sm.g0.Bs +
              (wn * 64 + nf * 16 + lane) * 128 + (((ks * 4 + quad) ^ (lane & 7)) * 16));
        #pragma unroll
        for (int mf = 0; mf < 4; ++mf)
          #pragma unroll
          for (int nf = 0; nf < 4; ++nf)
            acc[mf][nf] = __builtin_amdgcn_mfma_f32_16x16x32_bf16(
                af[mf], bf[nf], acc[mf][nf], 0, 0, 0);
      }
    }

    float bb[4];
    #pragma unroll
    for (int nf = 0; nf < 4; ++nf) bb[nf] = bsel[n_base + wn * 64 + nf * 16 + lane];

    u16* osel = (src == 0) ? Qb : (src == 1 ? Kb : VTb);

    #pragma unroll
    for (int mf = 0; mf < 4; ++mf) {
      int mb = m0 + wm * 64 + mf * 16 + quad * 4;
      #pragma unroll
      for (int nf = 0; nf < 4; ++nf) {
        int n_l = wn * 64 + nf * 16 + lane;
        if (src != 1) {
          // Q (scaled) and V: transposed [B,H,Dh,S], packed uint2 stores
          float sc = (src == 0) ? QSCALE : 1.0f;
          float v0 = (acc[mf][nf][0] + bb[nf]) * sc;
          float v1 = (acc[mf][nf][1] + bb[nf]) * sc;
          float v2 = (acc[mf][nf][2] + bb[nf]) * sc;
          float v3 = (acc[mf][nf][3] + bb[nf]) * sc;
          int bi = mb >> 11, s = mb & 2047;
          int n_in = n_base + n_l;
          int h = n_in >> 6, dh = n_in & 63;
          uint2 pk = make_uint2(cvtpk(v0, v1), cvtpk(v2, v3));
          *(uint2*)(osel + (((size_t)(bi * 16 + h) * 64 + dh) * 2048 + s)) = pk;
        } else {
          #pragma unroll
          for (int r = 0; r < 4; ++r) {
            float v = acc[mf][nf][r] + bb[nf];
            int m = mb + r;
            int bi = m >> 11, s = m & 2047;
            int n_in = n_base + n_l;
            int h = n_in >> 6, dh = n_in & 63;
            osel[(((size_t)(bi * 16 + h) * 2048 + s) << 6) + dh] = f2bf(v);
          }
        }
      }
    }
  }
  gbar(ctr + 1, 1024);

  // ================== phase 2: attn v13 (1024 jobs, 1:1) ==================
  {
    const int g = w >> 1;       // pair index: q rows g*32..+31 (of block's 64)
    const int kh = w & 1;       // key half
    const int lid = (idb & 7) * 128 + (idb >> 3);
    const int bh = lid >> 5;          // b*16 + h
    const int q0 = (lid & 31) * 64;

    const u16* QTg = Qb + (size_t)bh * 64 * 2048;     // [dh][s]
    const u16* Kg  = Kb + (size_t)bh * 2048 * 64;     // [s][dh]
    const u16* VTg = VTb + (size_t)bh * 64 * 2048;    // [dh][s]

    const int rr = w * 16;      // wave's 16 staging rows (2 glds/tensor)

    // Q B-frags gathered from Q^T (once per block)
    const int qcol = q0 + g * 32 + lane;
    bf16x8 bq_[2][2];
    #pragma unroll
    for (int qf = 0; qf < 2; ++qf)
      #pragma unroll
      for (int ks = 0; ks < 2; ++ks) {
        bf16x8 v;
        #pragma unroll
        for (int jj = 0; jj < 8; ++jj)
          v[jj] = __builtin_bit_cast(__bf16,
              QTg[(size_t)(ks * 32 + quad * 8 + jj) * 2048 + qcol + qf * 16]);
        bq_[qf][ks] = v;
      }

    // stage tile 0 -> buf 0 (4 glds per wave)
    GLOAD_LDS16(Kg + (size_t)(rr + lrow) * 64 + c8, sm.am.K[0] + rr * 64);
    GLOAD_LDS16(Kg + (size_t)(rr + 8 + lrow) * 64 + c8, sm.am.K[0] + (rr + 8) * 64);
    GLOAD_LDS16(VTg + (size_t)(rr + lrow) * 2048 + c8, sm.am.V[0] + rr * 64);
    GLOAD_LDS16(VTg + (size_t)(rr + 8 + lrow) * 2048 + c8, sm.am.V[0] + (rr + 8) * 64);

    f32x4 oa[2][4] = {};
    float lsum[2] = {0.f, 0.f};

    for (int kt = 0; kt < 32; ++kt) {
      const int cur = kt & 1;
      asm volatile("s_waitcnt vmcnt(0)" ::: "memory");
      __builtin_amdgcn_s_barrier();
      asm volatile("" ::: "memory");

      if (kt < 31) {
        GLOAD_LDS16(Kg + (size_t)((kt + 1) * 64 + rr + lrow) * 64 + c8,
                    sm.am.K[cur ^ 1] + rr * 64);
        GLOAD_LDS16(Kg + (size_t)((kt + 1) * 64 + rr + 8 + lrow) * 64 + c8,
                    sm.am.K[cur ^ 1] + (rr + 8) * 64);
        GLOAD_LDS16(VTg + (size_t)(rr + lrow) * 2048 + (kt + 1) * 64 + c8,
                    sm.am.V[cur ^ 1] + rr * 64);
        GLOAD_LDS16(VTg + (size_t)(rr + 8 + lrow) * 2048 + (kt + 1) * 64 + c8,
                    sm.am.V[cur ^ 1] + (rr + 8) * 64);
      }

      // S^T = K·Q^T: sa[kf][qf], key = kh*32 + kf*16 + quad*4 + r
      f32x4 sa[2][2] = {};
      #pragma unroll
      for (int ks = 0; ks < 2; ++ks) {
        bf16x8 ak[2];
        #pragma unroll
        for (int kf = 0; kf < 2; ++kf)
          ak[kf] = *(const bf16x8*)((const char*)sm.am.K[cur] +
              (kh * 32 + kf * 16 + lane) * 128 + (((ks * 4 + quad) ^ (lane & 7)) * 16));
        #pragma unroll
        for (int kf = 0; kf < 2; ++kf)
          #pragma unroll
          for (int qf = 0; qf < 2; ++qf)
            sa[kf][qf] = __builtin_amdgcn_mfma_f32_16x16x32_bf16(
                ak[kf], bq_[qf][ks], sa[kf][qf], 0, 0, 0);
      }

      // exp2 + in-register P relayout (cvt_pk + double permlane swap, T12)
      bf16x8 ap[2];
      #pragma unroll
      for (int qf = 0; qf < 2; ++qf) {
        float x0 = __builtin_amdgcn_exp2f(sa[0][qf][0]);
        float x1 = __builtin_amdgcn_exp2f(sa[0][qf][1]);
        float x2 = __builtin_amdgcn_exp2f(sa[0][qf][2]);
        float x3 = __builtin_amdgcn_exp2f(sa[0][qf][3]);
        float y0 = __builtin_amdgcn_exp2f(sa[1][qf][0]);
        float y1 = __builtin_amdgcn_exp2f(sa[1][qf][1]);
        float y2 = __builtin_amdgcn_exp2f(sa[1][qf][2]);
        float y3 = __builtin_amdgcn_exp2f(sa[1][qf][3]);
        lsum[qf] += ((x0 + x1) + (x2 + x3)) + ((y0 + y1) + (y2 + y3));
        u32 X0 = cvtpk(x0, x1), X1 = cvtpk(x2, x3);
        u32 Y0 = cvtpk(y0, y1), Y1 = cvtpk(y2, y3);
        asm("v_permlane32_swap_b32 %0, %1" : "+v"(X0), "+v"(Y0));
        asm("v_permlane16_swap_b32 %0, %1" : "+v"(X0), "+v"(Y0));
        asm("v_permlane32_swap_b32 %0, %1" : "+v"(X1), "+v"(Y1));
        asm("v_permlane16_swap_b32 %0, %1" : "+v"(X1), "+v"(Y1));
        uint4 d4 = make_uint4(X0, X1, Y0, Y1);
        ap[qf] = __builtin_bit_cast(bf16x8, d4);
      }

      // O += P·V
      {
        bf16x8 bv_[4];
        #pragma unroll
        for (int df = 0; df < 4; ++df)
          bv_[df] = *(const bf16x8*)((const char*)sm.am.V[cur] +
              (df * 16 + lane) * 128 + (((kh * 4 + quad) ^ (lane & 7)) * 16));
        #pragma unroll
        for (int qf = 0; qf < 2; ++qf)
          #pragma unroll
          for (int df = 0; df < 4; ++df)
            oa[qf][df] = __builtin_amdgcn_mfma_f32_16x16x32_bf16(
                ap[qf], bv_[df], oa[qf][df], 0, 0, 0);
      }
    }

    #pragma unroll
    for (int qf = 0; qf < 2; ++qf) {
      lsum[qf] += __shfl_xor(lsum[qf], 16);
      lsum[qf] += __shfl_xor(lsum[qf], 32);
    }

    __syncthreads();  // main-loop LDS reads complete; safe to alias union
    if (kh == 1) {
      #pragma unroll
      for (int qf = 0; qf < 2; ++qf)
        #pragma unroll
        for (int df = 0; df < 4; ++df)
          #pragma unroll
          for (int r = 0; r < 4; ++r)
            sm.af.O[g][(qf * 16 + quad * 4 + r) * 64 + df * 16 + lane] = oa[qf][df][r];
      if (l < 16) {
        sm.af.L[g][l] = lsum[0];
        sm.af.L[g][16 + l] = lsum[1];
      }
    }
    __syncthreads();
    if (kh == 0) {
      const int b = bh >> 4, hh = bh & 15;
      u16* Ob = AOb + ((size_t)b * 2048 + q0 + g * 32) * 1024 + hh * 64;
      float ltot[2];
      #pragma unroll
      for (int qf = 0; qf < 2; ++qf)
        ltot[qf] = lsum[qf] + sm.af.L[g][qf * 16 + lane];
      #pragma unroll
      for (int qf = 0; qf < 2; ++qf)
        #pragma unroll
        for (int r = 0; r < 4; ++r) {
          float inv = 1.0f / __shfl(ltot[qf], quad * 4 + r, 16);
          int qrow = qf * 16 + quad * 4 + r;
          #pragma unroll
          for (int df = 0; df < 4; ++df) {
            float v = oa[qf][df][r] + sm.af.O[g][qrow * 64 + df * 16 + lane];
            Ob[(size_t)qrow * 1024 + df * 16 + lane] = f2bf(v * inv);
          }
        }
    }
  }
  gbar(ctr + 2, 1024);

  // ========= phase 3: gemm1 O-proj, 64x64, KU=2, 1024 jobs (1:1) ==========
  {
    const int xcd = idb & 7, j = idb >> 3;
    const int m_idx = (xcd >> 1) * 16 + (j & 15);     // 64 m-tiles
    const int n_idx = (xcd & 1) * 8 + (j >> 4);       // 16 n-tiles
    const int m0 = m_idx * 64;
    const int n0g = n_idx * 64;
    const int wm = w >> 1, wn = w & 1;

    f32x4 acc[2][2] = {};

    for (int kt = 0; kt < 1024; kt += 128) {
      __syncthreads();
      #pragma unroll
      for (int ku = 0; ku < 2; ++ku) {
        const u16* Ag = AOb + (size_t)m0 * 1024 + kt + ku * 64;
        const u16* Bg = wob + (size_t)n0g * 1024 + kt + ku * 64;
        {
          int rr = w * 16;
          GLOAD_LDS16(Ag + (size_t)(rr + lrow) * 1024 + c8, sm.g1.As[ku] + rr * 64);
          GLOAD_LDS16(Ag + (size_t)(rr + 8 + lrow) * 1024 + c8, sm.g1.As[ku] + (rr + 8) * 64);
          GLOAD_LDS16(Bg + (size_t)(rr + lrow) * 1024 + c8, sm.g1.Bs[ku] + rr * 64);
          GLOAD_LDS16(Bg + (size_t)(rr + 8 + lrow) * 1024 + c8, sm.g1.Bs[ku] + (rr + 8) * 64);
        }
      }
      __syncthreads();

      #pragma unroll
      for (int ku = 0; ku < 2; ++ku)
        #pragma unroll
        for (int ks = 0; ks < 2; ++ks) {
          bf16x8 af[2], bf[2];
          #pragma unroll
          for (int mf = 0; mf < 2; ++mf)
            af[mf] = *(const bf16x8*)((const char*)sm.g1.As[ku] +
                (wm * 32 + mf * 16 + lane) * 128 + (((ks * 4 + quad) ^ (lane & 7)) * 16));
          #pragma unroll
          for (int nf = 0; nf < 2; ++nf)
            bf[nf] = *(const bf16x8*)((const char*)sm.g1.Bs[ku] +
                (wn * 32 + nf * 16 + lane) * 128 + (((ks * 4 + quad) ^ (lane & 7)) * 16));
          #pragma unroll
          for (int mf = 0; mf < 2; ++mf)
            #pragma unroll
            for (int nf = 0; nf < 2; ++nf)
              acc[mf][nf] = __builtin_amdgcn_mfma_f32_16x16x32_bf16(
                  af[mf], bf[nf], acc[mf][nf], 0, 0, 0);
        }
    }

    float bb[2];
    #pragma unroll
    for (int nf = 0; nf < 2; ++nf) bb[nf] = bo[n0g + wn * 32 + nf * 16 + lane];

    #pragma unroll
    for (int mf = 0; mf < 2; ++mf) {
      int mb = m0 + wm * 32 + mf * 16 + quad * 4;
      #pragma unroll
      for (int nf = 0; nf < 2; ++nf) {
        int n_l = wn * 32 + nf * 16 + lane;
        #pragma unroll
        for (int r = 0; r < 4; ++r)
          y[(size_t)(mb + r) * 1024 + n0g + n_l] = acc[mf][nf][r] + bb[nf];
      }
    }
  }
}

// ---------------------------------------------------------------------------
// Workspace (u16): xb[4M] wq[1M] wk[1M] wv[1M] wo[1M] Q[4M] K[4M] VT[4M]
// AO[4M] = 24M u16 = 48 MB, + 16 B barrier counters at the tail.
// ---------------------------------------------------------------------------
extern "C" void kernel_launch(void* const* d_in, const int* in_sizes, int n_in,
                              void* d_out, int out_size, void* d_ws, size_t ws_size,
                              hipStream_t stream)
{
  (void)in_sizes; (void)n_in; (void)out_size; (void)ws_size;
  const float* x  = (const float*)d_in[0];
  const float* Wq = (const float*)d_in[1];
  const float* bq = (const float*)d_in[2];
  const float* Wk = (const float*)d_in[3];
  const float* bk = (const float*)d_in[4];
  const float* Wv = (const float*)d_in[5];
  const float* bv = (const float*)d_in[6];
  const float* Wo = (const float*)d_in[7];
  const float* bo = (const float*)d_in[8];
  float* y = (float*)d_out;

  const size_t NM = (size_t)4096 * 1024;
  u16* xb  = (u16*)d_ws;
  u16* wqb = xb + NM;
  u16* wkb = wqb + 1024 * 1024;
  u16* wvb = wkb + 1024 * 1024;
  u16* wob = wvb + 1024 * 1024;
  u16* Qb  = wob + 1024 * 1024;   // Q^T [B,H,Dh,S]
  u16* Kb  = Qb + NM;             // K   [B,H,S,Dh]
  u16* VTb = Kb + NM;             // V^T [B,H,Dh,S]
  u16* AOb = VTb + NM;
  u32* ctr = (u32*)(AOb + NM);    // 3 barrier counters (tail of 48 MB)

  hipMemsetAsync(ctr, 0, 16, stream);

  mega<<<1024, 256, 0, stream>>>(x, Wq, bq, Wk, bk, Wv, bv, Wo, bo,
                                 xb, wqb, wkb, wvb, wob,
                                 Qb, Kb, VTb, AOb, y, ctr);
}

// Round 14
// 169.317 us; speedup vs baseline: 3.2259x; 3.2259x over previous
//
#include <hip/hip_runtime.h>
#include <cstdint>
#include <cstddef>

// MemoryEfficientAttention: B=2, S=2048, D=1024, H=16, Dh=64
// Pipeline: cvt_all -> gemm0 (QKV) -> attn v14 -> gemm1 (O-proj).
// R13 post-mortem: persistent mega-kernel catastrophically regressed
// (546 us; grid-barrier threadfence wbl2/inv per block serialized and
// destroyed L2 locality -> MfmaUtil 5.6%). Launch gaps also bounded small.
// REVERTED to R11 base (171.9; 2D XCD chunking, KU=2 gemm1, no setprio).
// attn v14 (this round): softmax denominator via MFMA -- ls[qf] =
// mfma(P, ones, ls) sums P over the wave's 32 keys; C layout puts lsum at
// q = qf*16+quad*4+r replicated in all lanes, which is EXACTLY the row the
// epilogue needs. Removes 14 VALU adds/wave-iter + the shfl_xor reduce +
// the epilogue shfl, moving work from the 51%-busy VALU to the 28%-busy
// MFMA pipe (+2 MFMA/iter). Denominator now sums bf16-rounded P = the
// same values PV consumes (absmax headroom 4x, R2 passed at 1.95e-3).

typedef unsigned short u16;
typedef unsigned int u32;
typedef __bf16 bf16x8 __attribute__((ext_vector_type(8)));
typedef float f32x4 __attribute__((ext_vector_type(4)));

#define GLOAD_LDS16(gp, lp)                                                            \
  __builtin_amdgcn_global_load_lds((const __attribute__((address_space(1))) void*)(gp),\
                                   (__attribute__((address_space(3))) void*)(lp),      \
                                   16, 0, 0)

__device__ __forceinline__ u16 f2bf(float f) {  // round-to-nearest-even
  unsigned u = __builtin_bit_cast(unsigned, f);
  u = u + 0x7fffu + ((u >> 16) & 1u);
  return (u16)(u >> 16);
}

// two f32 -> packed bf16x2 (lo = a, hi = b), RNE, 1 instruction (gfx950)
__device__ __forceinline__ u32 cvtpk(float a, float b) {
  u32 r;
  asm("v_cvt_pk_bf16_f32 %0, %1, %2" : "=v"(r) : "v"(a), "v"(b));
  return r;
}

// scale folded into Q: attn uses exp2, so fold log2(e) too
#define QSCALE 0.1803368801111204f   // 0.125 * log2(e)

// ---------------------------------------------------------------------------
// Fused fp32 -> bf16 convert for x + 4 weight matrices (1 launch).
// ---------------------------------------------------------------------------
__global__ void cvt_all(const float* __restrict__ x,
                        const float* __restrict__ wq, const float* __restrict__ wk,
                        const float* __restrict__ wv, const float* __restrict__ wo,
                        u16* __restrict__ xb, u16* __restrict__ wqb,
                        u16* __restrict__ wkb, u16* __restrict__ wvb,
                        u16* __restrict__ wob) {
  int bx = blockIdx.x;
  const float* s; u16* d; int off;
  if (bx < 2048)      { s = x;  d = xb;  off = bx; }
  else if (bx < 2560) { s = wq; d = wqb; off = bx - 2048; }
  else if (bx < 3072) { s = wk; d = wkb; off = bx - 2560; }
  else if (bx < 3584) { s = wv; d = wvb; off = bx - 3072; }
  else                { s = wo; d = wob; off = bx - 3584; }
  int i = off * 2048 + threadIdx.x * 8;
  float4 a = *(const float4*)(s + i);
  float4 b = *(const float4*)(s + i + 4);
  uint4 o;
  o.x = f2bf(a.x) | ((u32)f2bf(a.y) << 16);
  o.y = f2bf(a.z) | ((u32)f2bf(a.w) << 16);
  o.z = f2bf(b.x) | ((u32)f2bf(b.y) << 16);
  o.w = f2bf(b.z) | ((u32)f2bf(b.w) << 16);
  *(uint4*)(d + i) = o;
}

// ---------------------------------------------------------------------------
// bf16 MFMA GEMM (single-buffer, KU K-subtiles per barrier pair):
// C[m][n] = sum_k A[m][k]*W[n][k] + b[n]
// BM x BN tile, BK=64*KU, XOR-chunk-swizzled LDS via global_load_lds(16B);
// each K-subtile is an independent 64-col LDS image (proven addressing).
// 2D XCD chunking: XCD (idb&7) owns a rectangle of the (m,n) tile grid
// (gemm0: 8m x 12n = 5.2 MB working set; gemm1: 16m x 8n = 3.1 MB ~ L2).
// MODE 0 (128x128, KU=1, grid 24x32, 3 blocks/CU): fused QKV (N=3072):
//   Q TRANSPOSED+scaled [B,H,Dh,S]; K [B,H,S,Dh]; V TRANSPOSED [B,H,Dh,S].
// MODE 1 (64x64, KU=2, grid 16x64, 32 KB LDS, 4 blocks/CU): O-proj, fp32.
// ---------------------------------------------------------------------------
template <int MODE, int BM, int BN>
__global__ __launch_bounds__(256, MODE == 0 ? 3 : 4) void gemm_mfma(
    const u16* __restrict__ A,
    const u16* __restrict__ W0, const u16* __restrict__ W1, const u16* __restrict__ W2,
    const float* __restrict__ b0, const float* __restrict__ b1, const float* __restrict__ b2,
    u16* __restrict__ o0, u16* __restrict__ o1, u16* __restrict__ o2,
    float* __restrict__ oF)
{
  constexpr int MF = BM / 32;     // m-frags per wave (wave owns BM/2 rows)
  constexpr int NF = BN / 32;     // n-frags per wave (wave owns BN/2 cols)
  constexpr int AG = BM / 32;     // A-staging glds per wave per subtile
  constexpr int BG = BN / 32;     // B-staging glds per wave per subtile
  constexpr int KU = (MODE == 0) ? 1 : 2;   // K-subtiles per barrier pair

  __shared__ __align__(16) u16 As[KU][BM * 64];
  __shared__ __align__(16) u16 Bs[KU][BN * 64];

  const int tid = threadIdx.x;
  const int w = tid >> 6, l = tid & 63;
  const int lane = l & 15, quad = l >> 4;
  const int wm = w >> 1, wn = w & 1;

  // 2D XCD chunking: xcd = idb&7 -> rectangle; j walks m-fastest.
  const int idb = blockIdx.y * gridDim.x + blockIdx.x;
  const int xcd = idb & 7, j = idb >> 3;
  int m_idx, n_idx;
  if (MODE == 0) {          // 32m x 24n -> per XCD 8m x 12n
    m_idx = (xcd >> 1) * 8 + (j & 7);
    n_idx = (xcd & 1) * 12 + (j >> 3);
  } else {                  // 64m x 16n -> per XCD 16m x 8n
    m_idx = (xcd >> 1) * 16 + (j & 15);
    n_idx = (xcd & 1) * 8 + (j >> 4);
  }
  const int m0 = m_idx * BM;
  const int n0g = n_idx * BN;

  const int src = (MODE == 0) ? (n0g >> 10) : 0;
  const u16* Wsel = (MODE == 0) ? (src == 0 ? W0 : (src == 1 ? W1 : W2)) : W0;
  const float* bsel = (MODE == 0) ? (src == 0 ? b0 : (src == 1 ? b1 : b2)) : b0;
  const int n_base = (MODE == 0) ? (n0g & 1023) : n0g;

  const int c8 = ((l & 7) ^ (l >> 3)) * 8;
  const int lrow = l >> 3;

  f32x4 acc[MF][NF] = {};

  for (int kt = 0; kt < 1024; kt += 64 * KU) {
    __syncthreads();
    #pragma unroll
    for (int ku = 0; ku < KU; ++ku) {
      const u16* Ag = A + (size_t)m0 * 1024 + kt + ku * 64;
      const u16* Bg = Wsel + (size_t)n_base * 1024 + kt + ku * 64;
      #pragma unroll
      for (int i = 0; i < AG; ++i) {
        int rr = w * (8 * AG) + i * 8;
        GLOAD_LDS16(Ag + (size_t)(rr + lrow) * 1024 + c8, As[ku] + rr * 64);
      }
      #pragma unroll
      for (int i = 0; i < BG; ++i) {
        int rr = w * (8 * BG) + i * 8;
        GLOAD_LDS16(Bg + (size_t)(rr + lrow) * 1024 + c8, Bs[ku] + rr * 64);
      }
    }
    __syncthreads();

    #pragma unroll
    for (int ku = 0; ku < KU; ++ku) {
      bf16x8 af[MF][2], bf[NF][2];
      #pragma unroll
      for (int mf = 0; mf < MF; ++mf)
        #pragma unroll
        for (int ks = 0; ks < 2; ++ks)
          af[mf][ks] = *(const bf16x8*)((const char*)As[ku] +
              (wm * (BM / 2) + mf * 16 + lane) * 128 + (((ks * 4 + quad) ^ (lane & 7)) * 16));
      #pragma unroll
      for (int nf = 0; nf < NF; ++nf)
        #pragma unroll
        for (int ks = 0; ks < 2; ++ks)
          bf[nf][ks] = *(const bf16x8*)((const char*)Bs[ku] +
              (wn * (BN / 2) + nf * 16 + lane) * 128 + (((ks * 4 + quad) ^ (lane & 7)) * 16));
      #pragma unroll
      for (int ks = 0; ks < 2; ++ks)
        #pragma unroll
        for (int mf = 0; mf < MF; ++mf)
          #pragma unroll
          for (int nf = 0; nf < NF; ++nf)
            acc[mf][nf] = __builtin_amdgcn_mfma_f32_16x16x32_bf16(
                af[mf][ks], bf[nf][ks], acc[mf][nf], 0, 0, 0);
    }
  }

  float bb[NF];
  #pragma unroll
  for (int nf = 0; nf < NF; ++nf)
    bb[nf] = bsel[n_base + wn * (BN / 2) + nf * 16 + lane];

  u16* osel = (MODE == 0) ? (src == 0 ? o0 : (src == 1 ? o1 : o2)) : o0;

  #pragma unroll
  for (int mf = 0; mf < MF; ++mf) {
    int mb = m0 + wm * (BM / 2) + mf * 16 + quad * 4;
    #pragma unroll
    for (int nf = 0; nf < NF; ++nf) {
      int n_l = wn * (BN / 2) + nf * 16 + lane;
      if (MODE == 0 && src != 1) {
        // Q (scaled) and V: transposed [B,H,Dh,S], packed uint2 stores
        float sc = (src == 0) ? QSCALE : 1.0f;
        float v0 = (acc[mf][nf][0] + bb[nf]) * sc;
        float v1 = (acc[mf][nf][1] + bb[nf]) * sc;
        float v2 = (acc[mf][nf][2] + bb[nf]) * sc;
        float v3 = (acc[mf][nf][3] + bb[nf]) * sc;
        int bi = mb >> 11, s = mb & 2047;
        int n_in = n_base + n_l;
        int h = n_in >> 6, dh = n_in & 63;
        uint2 pk = make_uint2(cvtpk(v0, v1), cvtpk(v2, v3));
        *(uint2*)(osel + (((size_t)(bi * 16 + h) * 64 + dh) * 2048 + s)) = pk;
      } else {
        #pragma unroll
        for (int r = 0; r < 4; ++r) {
          float v = acc[mf][nf][r] + bb[nf];
          int m = mb + r;
          if (MODE == 0) {
            // K: [B,H,S,Dh], scalar stores
            int bi = m >> 11, s = m & 2047;
            int n_in = n_base + n_l;
            int h = n_in >> 6, dh = n_in & 63;
            osel[(((size_t)(bi * 16 + h) * 2048 + s) << 6) + dh] = f2bf(v);
          } else {
            oF[(size_t)m * 1024 + n0g + n_l] = v;
          }
        }
      }
    }
  }
}

// ---------------------------------------------------------------------------
// Flash attention v14: 512 threads = 8 waves = 4 PAIRS. Pair g owns q rows
// g*32..+31; wave kh handles keys kh*32..+31 of each tile. Per wave-tile:
// ak 4 + bv 4 = 8 ds_read_b128; P in registers (cvt_pk + double permlane).
// NEW: lsum via MFMA with all-ones B (ls[qf] = mfma(P, 1, ls)): C layout
// lands the denominator at q = qf*16+quad*4+r in EVERY lane -- exactly the
// epilogue's row index -- removing 14 VALU adds/iter + all lsum shuffles.
// Pipeline: K/V triple-buffered, raw s_barrier + s_waitcnt vmcnt(2),
// prefetch 2 tiles ahead. LDS = 48 KB -> 2 blocks/CU. No setprio.
// ---------------------------------------------------------------------------
union SMemU {
  struct {
    u16 K[3][64 * 64];   // [key][dh]
    u16 V[3][64 * 64];   // [dh][key]
  } m;
  struct {
    float O[4][32 * 64]; // per-pair partial O [q][d]
    float L[4][32];      // per-pair partial lsum
  } f;
};

__global__ __launch_bounds__(512, 4) void attn_mfma(
    const u16* __restrict__ Qg_, const u16* __restrict__ Kg_,
    const u16* __restrict__ VTg_, u16* __restrict__ Og)
{
  __shared__ __align__(16) SMemU sm;

  const int tid = threadIdx.x;
  const int w = tid >> 6, l = tid & 63;
  const int lane = l & 15, quad = l >> 4;
  const int g = w >> 1;       // pair index: q rows g*32..+31
  const int kh = w & 1;       // key half: keys kh*32..+31 of each tile

  // XCD-aware bijective remap: 64 block-ids per XCD = 4 heads x 16 q-blocks
  const int idb = blockIdx.y * 16 + blockIdx.x;
  const int lid = (idb & 7) * 64 + (idb >> 3);
  const int bh = lid >> 4;          // b*16 + h
  const int q0 = (lid & 15) * 128;

  const u16* QTg = Qg_ + (size_t)bh * 64 * 2048;    // [dh][s]
  const u16* Kg  = Kg_ + (size_t)bh * 2048 * 64;    // [s][dh]
  const u16* VTg = VTg_ + (size_t)bh * 64 * 2048;   // [dh][s]

  const int c8 = ((l & 7) ^ (l >> 3)) * 8;   // staging chunk swizzle
  const int lrow = l >> 3;
  const int rr = w * 8;       // this wave's 8 staging rows (1 glds per tensor)

  // all-ones bf16 B-operand for the lsum MFMA (splat constant)
  bf16x8 vone;
  #pragma unroll
  for (int jj = 0; jj < 8; ++jj) vone[jj] = (__bf16)1.0f;

  // Q B-frags gathered from Q^T (once per block; 32 scalar loads)
  const int qcol = q0 + g * 32 + lane;
  bf16x8 bq[2][2];
  #pragma unroll
  for (int qf = 0; qf < 2; ++qf)
    #pragma unroll
    for (int ks = 0; ks < 2; ++ks) {
      bf16x8 v;
      #pragma unroll
      for (int jj = 0; jj < 8; ++jj)
        v[jj] = __builtin_bit_cast(__bf16,
            QTg[(size_t)(ks * 32 + quad * 8 + jj) * 2048 + qcol + qf * 16]);
      bq[qf][ks] = v;
    }

  // stage tile 0 -> buf 0, tile 1 -> buf 1 (4 glds in flight per wave)
  GLOAD_LDS16(Kg + (size_t)(rr + lrow) * 64 + c8, sm.m.K[0] + rr * 64);
  GLOAD_LDS16(VTg + (size_t)(rr + lrow) * 2048 + c8, sm.m.V[0] + rr * 64);
  GLOAD_LDS16(Kg + (size_t)(64 + rr + lrow) * 64 + c8, sm.m.K[1] + rr * 64);
  GLOAD_LDS16(VTg + (size_t)(rr + lrow) * 2048 + 64 + c8, sm.m.V[1] + rr * 64);

  f32x4 oa[2][4] = {};
  f32x4 ls[2] = {};          // lsum accumulators (MFMA C): q = qf*16+quad*4+r
  int cur = 0;

  for (int kt = 0; kt < 32; ++kt) {
    // tile kt staged when OUR 2 oldest glds (tile kt) are done AND every
    // other wave's are too (barrier). Tile kt+1's 2 glds stay in flight.
    if (kt < 31) asm volatile("s_waitcnt vmcnt(2)" ::: "memory");
    else         asm volatile("s_waitcnt vmcnt(0)" ::: "memory");
    __builtin_amdgcn_s_barrier();
    asm volatile("" ::: "memory");

    // prefetch tile kt+2 into the buffer all waves finished at iter kt-1
    if (kt < 30) {
      int pf = (cur == 0) ? 2 : cur - 1;   // (cur+2)%3
      GLOAD_LDS16(Kg + (size_t)((kt + 2) * 64 + rr + lrow) * 64 + c8,
                  sm.m.K[pf] + rr * 64);
      GLOAD_LDS16(VTg + (size_t)(rr + lrow) * 2048 + (kt + 2) * 64 + c8,
                  sm.m.V[pf] + rr * 64);
    }

    // S^T = K·Q^T over this wave's 32 keys:
    // sa[kf][qf]: key = kh*32 + kf*16 + quad*4 + r, q = qf*16 + lane
    f32x4 sa[2][2] = {};
    #pragma unroll
    for (int ks = 0; ks < 2; ++ks) {
      bf16x8 ak[2];
      #pragma unroll
      for (int kf = 0; kf < 2; ++kf)
        ak[kf] = *(const bf16x8*)((const char*)sm.m.K[cur] +
            (kh * 32 + kf * 16 + lane) * 128 + (((ks * 4 + quad) ^ (lane & 7)) * 16));
      #pragma unroll
      for (int kf = 0; kf < 2; ++kf)
        #pragma unroll
        for (int qf = 0; qf < 2; ++qf)
          sa[kf][qf] = __builtin_amdgcn_mfma_f32_16x16x32_bf16(
              ak[kf], bq[qf][ks], sa[kf][qf], 0, 0, 0);
    }

    // softmax numerator (bare exp2) + in-register P relayout:
    // X pair (kf=0) / Y pair (kf=1) -> cvt_pk -> double permlane swap ->
    // PV A-frags (T12). lsum is NOT accumulated on VALU -- see below.
    bf16x8 ap[2];
    #pragma unroll
    for (int qf = 0; qf < 2; ++qf) {
      float x0 = __builtin_amdgcn_exp2f(sa[0][qf][0]);
      float x1 = __builtin_amdgcn_exp2f(sa[0][qf][1]);
      float x2 = __builtin_amdgcn_exp2f(sa[0][qf][2]);
      float x3 = __builtin_amdgcn_exp2f(sa[0][qf][3]);
      float y0 = __builtin_amdgcn_exp2f(sa[1][qf][0]);
      float y1 = __builtin_amdgcn_exp2f(sa[1][qf][1]);
      float y2 = __builtin_amdgcn_exp2f(sa[1][qf][2]);
      float y3 = __builtin_amdgcn_exp2f(sa[1][qf][3]);
      u32 X0 = cvtpk(x0, x1), X1 = cvtpk(x2, x3);
      u32 Y0 = cvtpk(y0, y1), Y1 = cvtpk(y2, y3);
      asm("v_permlane32_swap_b32 %0, %1" : "+v"(X0), "+v"(Y0));
      asm("v_permlane16_swap_b32 %0, %1" : "+v"(X0), "+v"(Y0));
      asm("v_permlane32_swap_b32 %0, %1" : "+v"(X1), "+v"(Y1));
      asm("v_permlane16_swap_b32 %0, %1" : "+v"(X1), "+v"(Y1));
      uint4 d4 = make_uint4(X0, X1, Y0, Y1);  // A-frag dwords 0..3
      ap[qf] = __builtin_bit_cast(bf16x8, d4);
    }

    // lsum via MFMA: ls[qf] += P · ones  (sums the wave's 32 keys per q-row;
    // result at q = qf*16 + quad*4 + r, replicated across all lanes)
    #pragma unroll
    for (int qf = 0; qf < 2; ++qf)
      ls[qf] = __builtin_amdgcn_mfma_f32_16x16x32_bf16(
          ap[qf], vone, ls[qf], 0, 0, 0);

    // O += P·V over this wave's 32 keys (single mfma16 K-depth):
    {
      bf16x8 bv[4];
      #pragma unroll
      for (int df = 0; df < 4; ++df)
        bv[df] = *(const bf16x8*)((const char*)sm.m.V[cur] +
            (df * 16 + lane) * 128 + (((kh * 4 + quad) ^ (lane & 7)) * 16));
      #pragma unroll
      for (int qf = 0; qf < 2; ++qf)
        #pragma unroll
        for (int df = 0; df < 4; ++df)
          oa[qf][df] = __builtin_amdgcn_mfma_f32_16x16x32_bf16(
              ap[qf], bv[df], oa[qf][df], 0, 0, 0);
    }

    cur = (cur == 2) ? 0 : cur + 1;
  }

  // ---- pair combine: kh=1 wave publishes partials, kh=0 wave merges ----
  __syncthreads();  // main-loop LDS reads complete; safe to alias via union
  if (kh == 1) {
    #pragma unroll
    for (int qf = 0; qf < 2; ++qf)
      #pragma unroll
      for (int df = 0; df < 4; ++df)
        #pragma unroll
        for (int r = 0; r < 4; ++r)
          sm.f.O[g][(qf * 16 + quad * 4 + r) * 64 + df * 16 + lane] = oa[qf][df][r];
    if (lane == 0) {
      #pragma unroll
      for (int qf = 0; qf < 2; ++qf)
        #pragma unroll
        for (int r = 0; r < 4; ++r)
          sm.f.L[g][qf * 16 + quad * 4 + r] = ls[qf][r];
    }
  }
  __syncthreads();
  if (kh == 0) {
    const int b = bh >> 4, hh = bh & 15;
    u16* Ob = Og + ((size_t)b * 2048 + q0 + g * 32) * 1024 + hh * 64;
    float inv[2][4];
    #pragma unroll
    for (int qf = 0; qf < 2; ++qf)
      #pragma unroll
      for (int r = 0; r < 4; ++r)
        inv[qf][r] = 1.0f / (ls[qf][r] + sm.f.L[g][qf * 16 + quad * 4 + r]);
    #pragma unroll
    for (int qf = 0; qf < 2; ++qf)
      #pragma unroll
      for (int r = 0; r < 4; ++r) {
        int qrow = qf * 16 + quad * 4 + r;
        #pragma unroll
        for (int df = 0; df < 4; ++df) {
          float v = oa[qf][df][r] + sm.f.O[g][qrow * 64 + df * 16 + lane];
          Ob[(size_t)qrow * 1024 + df * 16 + lane] = f2bf(v * inv[qf][r]);
        }
      }
  }
}

// ---------------------------------------------------------------------------
// Workspace (u16): xb[4M] wq[1M] wk[1M] wv[1M] wo[1M] Q[4M] K[4M] VT[4M]
// AO[4M] = 24M u16 = 48 MB.
// ---------------------------------------------------------------------------
extern "C" void kernel_launch(void* const* d_in, const int* in_sizes, int n_in,
                              void* d_out, int out_size, void* d_ws, size_t ws_size,
                              hipStream_t stream)
{
  (void)in_sizes; (void)n_in; (void)out_size; (void)ws_size;
  const float* x  = (const float*)d_in[0];
  const float* Wq = (const float*)d_in[1];
  const float* bq = (const float*)d_in[2];
  const float* Wk = (const float*)d_in[3];
  const float* bk = (const float*)d_in[4];
  const float* Wv = (const float*)d_in[5];
  const float* bv = (const float*)d_in[6];
  const float* Wo = (const float*)d_in[7];
  const float* bo = (const float*)d_in[8];
  float* y = (float*)d_out;

  const size_t NM = (size_t)4096 * 1024;
  u16* xb  = (u16*)d_ws;
  u16* wqb = xb + NM;
  u16* wkb = wqb + 1024 * 1024;
  u16* wvb = wkb + 1024 * 1024;
  u16* wob = wvb + 1024 * 1024;
  u16* Qb  = wob + 1024 * 1024;   // Q^T [B,H,Dh,S]
  u16* Kb  = Qb + NM;             // K   [B,H,S,Dh]
  u16* VTb = Kb + NM;             // V^T [B,H,Dh,S]
  u16* AOb = VTb + NM;

  cvt_all<<<4096, 256, 0, stream>>>(x, Wq, Wk, Wv, Wo, xb, wqb, wkb, wvb, wob);

  gemm_mfma<0, 128, 128><<<dim3(24, 32), 256, 0, stream>>>(
      xb, wqb, wkb, wvb, bq, bk, bv, Qb, Kb, VTb, nullptr);

  attn_mfma<<<dim3(16, 32), 512, 0, stream>>>(Qb, Kb, VTb, AOb);

  gemm_mfma<1, 64, 64><<<dim3(16, 64), 256, 0, stream>>>(
      AOb, wob, nullptr, nullptr, bo, nullptr, nullptr,
      nullptr, nullptr, nullptr, y);
}